// Round 17
// baseline (1836.048 us; speedup 1.0000x reference)
//
#include <hip/hip_runtime.h>

#define L_ 6
#define D_ 1024
#define H_ 8
#define F_ 2048
#define B_ 4
#define S_ 2048
#define IN_ 128
#define DK_ 128
#define BS_ (B_*S_)
#define D2_ 4096     // fused qkvg row stride

typedef short bf16x8 __attribute__((ext_vector_type(8)));
typedef float f32x4 __attribute__((ext_vector_type(4)));

__device__ inline float b2f(unsigned short u){ union{unsigned int i; float f;} v; v.i = ((unsigned int)u)<<16; return v.f; }
__device__ inline unsigned short f2b(float f){ union{unsigned int i; float f;} v; v.f = f; unsigned int r = v.i + 0x7FFFu + ((v.i>>16)&1u); return (unsigned short)(r>>16); }
__device__ inline unsigned int cvtpk(float lo, float hi){
    unsigned int r; asm("v_cvt_pk_bf16_f32 %0, %1, %2" : "=v"(r) : "v"(lo), "v"(hi)); return r;
}

__device__ inline void gld16(const void* g, void* l) {
    __builtin_amdgcn_global_load_lds((const __attribute__((address_space(1))) unsigned int*)g,
                                     (__attribute__((address_space(3))) unsigned int*)l, 16, 0, 0);
}

#define GBAR() do{ asm volatile("" ::: "memory"); __builtin_amdgcn_s_barrier(); asm volatile("" ::: "memory"); }while(0)

// ---------------- elementwise convert ----------------
__global__ void f32_to_bf16_k(const float* __restrict__ in, unsigned short* __restrict__ out, int n)
{
    int i = blockIdx.x*256 + threadIdx.x;
    if (i < n) out[i] = f2b(in[i]);
}

// ---------------- weight transpose-convert: out[z*ostride + c*R + r] = in[z][r][c] ----------------
__global__ void transpose_w_k(const float* __restrict__ in, unsigned short* __restrict__ out, int R, int C, size_t ostride)
{
    __shared__ float tile[32][33];
    int z = blockIdx.z;
    const float* pi = in + (size_t)z*R*C;
    unsigned short* po = out + (size_t)z*ostride;
    int c0 = blockIdx.x*32, r0 = blockIdx.y*32;
    int tx = threadIdx.x, ty = threadIdx.y;
    #pragma unroll
    for (int i=0;i<4;i++) tile[ty+i*8][tx] = pi[(size_t)(r0+ty+i*8)*C + c0+tx];
    __syncthreads();
    #pragma unroll
    for (int i=0;i<4;i++) po[(size_t)(c0+ty+i*8)*R + r0+tx] = f2b(tile[tx][ty+i*8]);
}

// ---------------- fused RoPE (q,k in-place) + v transpose to (B,H,DK,S) ----------------
// grid (S/32, DK/32, B*H), block (32,8)
__global__ void rope_vt_k(unsigned short* __restrict__ qkvg, unsigned short* __restrict__ vT,
                          const float* __restrict__ cost, const float* __restrict__ sint)
{
    __shared__ unsigned short tile[32][33];
    int z = blockIdx.z;             // b*H + h
    int b = z >> 3, hh = z & 7;
    int s0 = blockIdx.x*32, d0 = blockIdx.y*32;
    int tx = threadIdx.x, ty = threadIdx.y;
    const unsigned short* vb = qkvg + 2048;
    #pragma unroll
    for (int i=0;i<4;i++) tile[ty+i*8][tx] = vb[(size_t)(b*S_ + s0+ty+i*8)*D2_ + hh*DK_ + d0+tx];

    // rope: 512 (row, pair) items over 256 threads
    int t = ty*32 + tx;
    #pragma unroll
    for (int it=0; it<2; ++it) {
        int idx = it*256 + t;
        int row = idx >> 4;            // 0..31
        int pr  = idx & 15;            // pair in 0..15
        int s  = s0 + row;
        int dk = d0 + pr*2;
        float c0 = cost[s*DK_ + dk],   sn0 = sint[s*DK_ + dk];
        float c1 = cost[s*DK_ + dk+1], sn1 = sint[s*DK_ + dk+1];
        size_t off = (size_t)(b*S_ + s)*D2_ + hh*DK_ + dk;
        unsigned int qu = *(unsigned int*)(qkvg + off);
        float q0 = b2f((unsigned short)(qu & 0xffffu)), q1 = b2f((unsigned short)(qu >> 16));
        float r0 = q0*c0 - q1*sn0;
        float r1 = q1*c1 + q0*sn1;
        *(unsigned int*)(qkvg + off) = (unsigned int)f2b(r0) | ((unsigned int)f2b(r1) << 16);
        const float sc = 0.08838834764831845f;
        unsigned int ku = *(unsigned int*)(qkvg + off + 1024);
        float k0 = b2f((unsigned short)(ku & 0xffffu))*sc, k1 = b2f((unsigned short)(ku >> 16))*sc;
        float t0 = k0*c0 - k1*sn0;
        float t1 = k1*c1 + k0*sn1;
        *(unsigned int*)(qkvg + off + 1024) = (unsigned int)f2b(t0) | ((unsigned int)f2b(t1) << 16);
    }

    __syncthreads();
    #pragma unroll
    for (int i=0;i<4;i++) vT[((size_t)z*DK_ + d0+ty+i*8)*S_ + s0+tx] = tile[tx][ty+i*8];
}

// ---------------- tables ----------------
__global__ void build_sincos_k(float* __restrict__ cost, float* __restrict__ sint)
{
    int id = blockIdx.x*256 + threadIdx.x;     // S*64
    int s = id >> 6, i = id & 63;
    float ang = powf(10000.f, -(float)i/63.f);
    float a = (float)s * ang;
    float sv = sinf(a), cv = cosf(a);
    sint[s*DK_ + 2*i] = sv; sint[s*DK_ + 2*i+1] = sv;
    cost[s*DK_ + 2*i] = cv; cost[s*DK_ + 2*i+1] = cv;
}

__global__ void build_dnorm_k(float* __restrict__ dnorm)
{
    int id = blockIdx.x*256 + threadIdx.x;     // H*S
    int h = id >> 11, n = id & (S_-1);
    double g = 1.0 - exp2((double)(-5 - h));
    double sum = (1.0 - exp(((double)(n+1))*log(g))) / (1.0 - g);
    dnorm[id] = (float)(1.0/sqrt(sum));
}

// ---------------- block reduce helper (256 threads) ----------------
__device__ inline float bsum(float v, float* red, int t)
{
    #pragma unroll
    for (int m=32; m; m>>=1) v += __shfl_xor(v, m);
    __syncthreads();
    if ((t & 63) == 0) red[t>>6] = v;
    __syncthreads();
    return red[0]+red[1]+red[2]+red[3];
}

// ---------------- layernorm (bf16 in) -> bf16 ----------------
__global__ __launch_bounds__(256) void ln_to_bf16_k(const unsigned short* __restrict__ x, const float* __restrict__ s,
                                                    const float* __restrict__ b, unsigned short* __restrict__ y)
{
    __shared__ float red[4];
    int row = blockIdx.x, t = threadIdx.x;
    const unsigned short* xr = x + (size_t)row * D_;
    ushort4 u = ((const ushort4*)xr)[t];
    float v0=b2f(u.x), v1=b2f(u.y), v2=b2f(u.z), v3=b2f(u.w);
    float mu = bsum(v0+v1+v2+v3, red, t) * (1.f/D_);
    float d0=v0-mu, d1=v1-mu, d2=v2-mu, d3=v3-mu;
    float var = bsum(d0*d0+d1*d1+d2*d2+d3*d3, red, t) * (1.f/D_);
    float inv = rsqrtf(var + 1e-6f);
    int c = t*4;
    float o0 = d0*inv*s[c+0] + b[c+0];
    float o1 = d1*inv*s[c+1] + b[c+1];
    float o2 = d2*inv*s[c+2] + b[c+2];
    float o3 = d3*inv*s[c+3] + b[c+3];
    unsigned long long pk = (unsigned long long)f2b(o0) | ((unsigned long long)f2b(o1)<<16)
                          | ((unsigned long long)f2b(o2)<<32) | ((unsigned long long)f2b(o3)<<48);
    *(unsigned long long*)(y + (size_t)row*D_ + c) = pk;
}

// ============ GEMM v10 hybrid: BMxBN tile, BK=64, 2-buffer LDS ============
// C[M,N] = A[M,K] @ Bt[N,K]^T, 512 threads, 8 waves (2M x 4N)
// BN=256: per-kk single phase, staggered half-batch staging, counted vmcnt(4). 4 barriers/tile.
// BN=128 (round-13 schedule): full batch(t+1) at kk0, vmcnt(2Sa) kk0-end / vmcnt(Sa) kk1-end.
// MODE 0: bias+store bf16   1: bf16 RMW accumulate (+bias)   2: store bf16   3: bias+gelu -> bf16
template<int MODE, int BM, int BN>
__global__ __launch_bounds__(512, 2)
void gemm6(const unsigned short* __restrict__ A,
           const unsigned short* __restrict__ Bt,
           const float* __restrict__ bias,
           void* __restrict__ Cv,
           int M, int N, int K)
{
    constexpr int IR   = BM/2/16;         // 8 or 4
    constexpr int JR   = BN/64;           // 4 or 2
    constexpr int ASUB = BM*64;           // bytes per A K-subtile
    constexpr int BSUB = BN*64;
    constexpr int BUFSZ= 2*ASUB + 2*BSUB;
    constexpr int AP   = BM/128;          // gld16 passes per subtile
    constexpr int BP   = BN/128;
    constexpr int Sa   = AP + BP;         // gld16 per thread per K-subtile (kk)
    __shared__ unsigned char lds[2*BUFSZ];

    const int tid = threadIdx.x, lane = tid & 63, w = tid >> 6;
    const int r16 = lane & 15, quad = (lane >> 4) & 3;
    const int wm = w >> 2, wn = w & 3;

    // XCD-aware bijective block swizzle (grid % 8 == 0 in all our launches)
    const int nwg = (int)(gridDim.x * gridDim.y);
    int bid = (int)(blockIdx.y * gridDim.x + blockIdx.x);
    if ((nwg & 7) == 0) bid = (bid & 7) * (nwg >> 3) + (bid >> 3);
    const int m0 = (bid / (int)gridDim.x) * BM;
    const int n0 = (bid % (int)gridDim.x) * BN;

    // staging: thread -> (row = tid>>2, chunk = tid&3); source chunk inverse-swizzled
    const int srow = tid >> 2;
    const int schk = (tid & 3) ^ ((tid >> 3) & 3);
    const unsigned short* gA = A  + (size_t)(m0 + srow) * K + schk*8;
    const unsigned short* gB = Bt + (size_t)(n0 + srow) * K + schk*8;

    // swizzled read chunk (row bases multiples of 16 -> (row>>1)&3 == (r16>>1)&3)
    const int rchk = (quad ^ ((r16 >> 1) & 3)) * 16;
    const int aoff = (wm*(BM/2) + r16)*64 + rchk;
    const int boff = (wn*(BN/4) + r16)*64 + rchk;

    f32x4 acc[IR][JR];
    #pragma unroll
    for (int i=0;i<IR;i++)
      #pragma unroll
      for (int j=0;j<JR;j++) acc[i][j] = (f32x4){0.f,0.f,0.f,0.f};

    const int NT = K >> 6;   // 64-K tiles

    auto stageA = [&](int t, int kk){
        unsigned char* dst = lds + (t&1)*BUFSZ + kk*ASUB;
        const unsigned short* src = gA + (size_t)t*64 + kk*32;
        #pragma unroll
        for (int p=0;p<AP;p++)
            gld16(src + (size_t)(p*128)*K, dst + p*8192 + tid*16);
    };
    auto stageB = [&](int t, int kk){
        unsigned char* dst = lds + (t&1)*BUFSZ + 2*ASUB + kk*BSUB;
        const unsigned short* src = gB + (size_t)t*64 + kk*32;
        #pragma unroll
        for (int p=0;p<BP;p++)
            gld16(src + (size_t)(p*128)*K, dst + p*8192 + tid*16);
    };

    #define WAIT_N(nn) asm volatile("s_waitcnt vmcnt(" #nn ")" ::: "memory")
    #define WAIT_SA()  do{ if constexpr (Sa==4) WAIT_N(4); else WAIT_N(2); }while(0)
    #define WAIT_2SA() do{ if constexpr (Sa==4) WAIT_N(8); else WAIT_N(4); }while(0)

    // prologue: tile 0 staged (kk0 then kk1); land kk0 half, leave kk1 in flight
    stageA(0,0); stageB(0,0); stageA(0,1); stageB(0,1);
    WAIT_SA();
    GBAR();

    for (int t = 0; t < NT; ++t) {
        const unsigned char* cb = lds + (t&1)*BUFSZ;
        const bool pre = (t+1 < NT);

        if constexpr (BN == 256) {
            // ======== per-kk single phase, staggered staging, counted vmcnt(4) ========
            #pragma unroll
            for (int kk = 0; kk < 2; ++kk) {
                const unsigned char* ak = cb + kk*ASUB;
                const unsigned char* bk = cb + 2*ASUB + kk*BSUB;
                bf16x8 af[8], bg[JR];
                #pragma unroll
                for (int i=0;i<8;i++) af[i] = *(const bf16x8*)(ak + aoff + i*1024);
                #pragma unroll
                for (int j=0;j<JR;j++) bg[j] = *(const bf16x8*)(bk + boff + j*1024);
                if (pre) { stageA(t+1, kk); stageB(t+1, kk); }
                GBAR();
                asm volatile("s_waitcnt lgkmcnt(0)" ::: "memory");
                __builtin_amdgcn_s_setprio(1);
                #pragma unroll
                for (int i=0;i<8;i++)
                  #pragma unroll
                  for (int j=0;j<JR;j++)
                    acc[i][j] = __builtin_amdgcn_mfma_f32_16x16x32_bf16(af[i], bg[j], acc[i][j], 0,0,0);
                __builtin_amdgcn_s_setprio(0);
                if (pre) { WAIT_SA(); }
                else     { WAIT_N(0); }
                GBAR();
            }
        } else {
            // ======== round-13 schedule: full batch at kk0, deep counted waits ========
            const unsigned char* ak0 = cb;
            const unsigned char* bk0 = cb + 2*ASUB;
            const unsigned char* ak1 = cb + ASUB;
            const unsigned char* bk1 = cb + 2*ASUB + BSUB;
            // ---- kk0 single phase ----
            bf16x8 af[IR], bg[JR];
            #pragma unroll
            for (int i=0;i<IR;i++) af[i] = *(const bf16x8*)(ak0 + aoff + i*1024);
            #pragma unroll
            for (int j=0;j<JR;j++) bg[j] = *(const bf16x8*)(bk0 + boff + j*1024);
            if (pre) { stageA(t+1,0); stageB(t+1,0); stageA(t+1,1); stageB(t+1,1); }
            GBAR();
            asm volatile("s_waitcnt lgkmcnt(0)" ::: "memory");
            __builtin_amdgcn_s_setprio(1);
            #pragma unroll
            for (int i=0;i<IR;i++)
              #pragma unroll
              for (int j=0;j<JR;j++)
                acc[i][j] = __builtin_amdgcn_mfma_f32_16x16x32_bf16(af[i], bg[j], acc[i][j], 0,0,0);
            __builtin_amdgcn_s_setprio(0);
            if (pre) { WAIT_2SA(); } else { WAIT_N(0); }
            GBAR();
            // ---- kk1 single phase ----
            #pragma unroll
            for (int i=0;i<IR;i++) af[i] = *(const bf16x8*)(ak1 + aoff + i*1024);
            #pragma unroll
            for (int j=0;j<JR;j++) bg[j] = *(const bf16x8*)(bk1 + boff + j*1024);
            GBAR();
            asm volatile("s_waitcnt lgkmcnt(0)" ::: "memory");
            __builtin_amdgcn_s_setprio(1);
            #pragma unroll
            for (int i=0;i<IR;i++)
              #pragma unroll
              for (int j=0;j<JR;j++)
                acc[i][j] = __builtin_amdgcn_mfma_f32_16x16x32_bf16(af[i], bg[j], acc[i][j], 0,0,0);
            __builtin_amdgcn_s_setprio(0);
            if (pre) { WAIT_SA(); }
            GBAR();
        }
    }
    #undef WAIT_N
    #undef WAIT_SA
    #undef WAIT_2SA

    // epilogue: (i,r)-outer, j-inner -> contiguous row segments in adjacent stores
    unsigned short* Cb = (unsigned short*)Cv;
    float bvs[JR];
    #pragma unroll
    for (int j=0;j<JR;j++) bvs[j] = bias ? bias[n0 + wn*(BN/4) + j*16 + r16] : 0.f;
    #pragma unroll
    for (int i=0;i<IR;i++) {
      #pragma unroll
      for (int r=0;r<4;r++) {
        const size_t crow = (size_t)(m0 + wm*(BM/2) + i*16 + quad*4 + r);
        #pragma unroll
        for (int j=0;j<JR;j++) {
          const int ccol = n0 + wn*(BN/4) + j*16 + r16;
          float v = acc[i][j][r];
          if (MODE == 0) { Cb[crow*N + ccol] = f2b(v + bvs[j]); }
          else if (MODE == 1) { Cb[crow*N + ccol] = f2b(b2f(Cb[crow*N + ccol]) + v + bvs[j]); }
          else if (MODE == 2) { Cb[crow*N + ccol] = f2b(v); }
          else {
            v += bvs[j];
            float t3 = tanhf(0.7978845608028654f*(v + 0.044715f*v*v*v));
            Cb[crow*N + ccol] = f2b(0.5f*v*(1.f + t3));
          }
        }
      }
    }
}

// ====== retention: 64-q-row tiles, diagonal pair per block, wave-split K (QK) / d (PV) ======
// XCD-locality remap: linear block L -> XCD k=L%8 owns bh in [4k,4k+4) so each XCD's
// K/V working set = 4 heads x 1MB = 4MB = its L2. P rows: 128B stride + chunk XOR (conflict-free).
// LDS: K dbuf 2x16KB @0; V dbuf 2x16KB @32768; P[64][64] 8KB @65536; dsums @73728; ssums @74752
__global__ __launch_bounds__(256, 2) void retention_k(const unsigned short* __restrict__ qk_base,
    const unsigned short* __restrict__ vT, const float* __restrict__ dnorm,
    const float* __restrict__ gng, unsigned short* __restrict__ attnin)
{
    __shared__ __align__(16) unsigned char lds[75776];
    const int Lf = (int)(blockIdx.y * gridDim.x + blockIdx.x);
    const int kx = Lf & 7, mm = Lf >> 3;
    const int bh = 4*kx + (mm >> 4);     // XCD kx serves bh 4kx..4kx+3
    const int pr = mm & 15;              // 0..15 : pair (31-pr, pr)
    const int b = bh >> 3, hh = bh & 7;
    const int tid = threadIdx.x, lane = tid & 63, w = tid >> 6;
    const int r16 = lane & 15, quad = lane >> 4;

    const float l2g = log2f(1.f - exp2f(-5.f - (float)hh));
    const int ithr = (int)(45.f / (-l2g));
    const unsigned int mkr = (r16 & 7) << 4;

    // staging sources (pre-swizzled global, linear LDS dest)
    const int mk2  = ((tid >> 4) & 7) << 4;
    const int mkv2 = ((tid >> 3) & 7) << 4;
    const unsigned short* ksrc = qk_base + 1024 + ((size_t)(b*S_) + (tid>>4))*D2_ + hh*DK_
                                + ((((tid&15)*16) ^ mk2) >> 1);
    const unsigned short* vsrc = vT + ((size_t)bh*DK_ + (tid>>3))*S_ + ((((tid&7)*16) ^ mkv2) >> 1);

    // key-side decay factor, loop-invariant: Aarr[r] = 2^(l2g*(63 - m_loc)), m_loc = w*16+quad*4+r
    float Aarr[4];
    #pragma unroll
    for (int r=0;r<4;r++) Aarr[r] = exp2f(l2g * (float)(63 - (w*16 + quad*4 + r)));

    float* dsums = (float*)(lds + 73728);
    float* ssums = (float*)(lds + 74752);

    auto stage = [&](int c2, int kt2){
        const unsigned short* s0 = ksrc + (size_t)kt2*64*D2_;
        #pragma unroll
        for (int i=0;i<4;i++)
            gld16(s0 + (size_t)i*16*D2_, lds + c2*16384 + i*4096 + w*1024);
        const unsigned short* s1 = vsrc + kt2*64;
        #pragma unroll
        for (int j=0;j<4;j++)
            gld16(s1 + (size_t)j*32*S_, lds + 32768 + c2*16384 + j*4096 + w*1024);
    };

    int cur = 0;

    #pragma unroll 1
    for (int seg = 0; seg < 2; ++seg) {
        const int qt = seg ? pr : (31 - pr);
        const int n0 = qt * 64;
        const int kt_start = max(0, (n0 - ithr) >> 6);

        // Q fragments (B-operand, all 64 q-cols): qf[qtile][c]
        bf16x8 qf[4][4];
        const unsigned short* qptr = qk_base + ((size_t)(b*S_ + n0 + r16))*D2_ + hh*DK_;
        #pragma unroll
        for (int qtl=0;qtl<4;qtl++)
          #pragma unroll
          for (int c=0;c<4;c++) qf[qtl][c] = *(const bf16x8*)(qptr + qtl*16*D2_ + c*32 + quad*8);

        f32x4 oacc[4][2];   // [qtile][dtile]; row=q(quad*4+r), col=d(w*32+dtile*16+r16)
        #pragma unroll
        for (int qtl=0;qtl<4;qtl++)
          #pragma unroll
          for (int dt=0;dt<2;dt++) oacc[qtl][dt] = (f32x4){0.f,0.f,0.f,0.f};
        float dsum[4] = {0.f,0.f,0.f,0.f};

        stage(cur, kt_start);

        #pragma unroll 1
        for (int kt = kt_start; kt <= qt; ++kt) {
            if (kt < qt) { stage(cur^1, kt+1); asm volatile("s_waitcnt vmcnt(8)" ::: "memory"); }
            else         { asm volatile("s_waitcnt vmcnt(0)" ::: "memory"); }
            GBAR();   // M1: K/V[cur] fully staged on all waves

            // ---- QK: wave w owns keys w*16..w*16+15 ----
            const unsigned char* kb = lds + cur*16384;
            bf16x8 kf[4];
            #pragma unroll
            for (int c=0;c<4;c++)
                kf[c] = *(const bf16x8*)(kb + (w*16 + r16)*256 + ((c*64 + quad*16) ^ mkr));
            f32x4 sf[4];
            #pragma unroll
            for (int qtl=0;qtl<4;qtl++) sf[qtl] = (f32x4){0.f,0.f,0.f,0.f};
            __builtin_amdgcn_s_setprio(1);
            #pragma unroll
            for (int c=0;c<4;c++)
              #pragma unroll
              for (int qtl=0;qtl<4;qtl++)
                sf[qtl] = __builtin_amdgcn_mfma_f32_16x16x32_bf16(kf[c], qf[qtl][c], sf[qtl], 0,0,0);
            __builtin_amdgcn_s_setprio(0);

            // ---- decay + mask + P write (P[q][k], 128B row stride, swizzled) ----
            const bool diag = (kt == qt);
            #pragma unroll
            for (int qtl=0;qtl<4;qtl++) {
                float Bq = exp2f(l2g * (float)(n0 + qtl*16 + r16 - kt*64 - 63));
                float pv[4];
                #pragma unroll
                for (int r=0;r<4;r++) {
                    float p = sf[qtl][r] * Aarr[r] * Bq;
                    if (diag && (w*16 + quad*4 + r > qtl*16 + r16)) p = 0.f;
                    dsum[qtl] += fabsf(p);
                    pv[r] = p;
                }
                unsigned long long pk = (unsigned long long)cvtpk(pv[0], pv[1])
                                      | ((unsigned long long)cvtpk(pv[2], pv[3]) << 32);
                *(unsigned long long*)(lds + 65536 + (qtl*16 + r16)*128 + ((w*32 + quad*8) ^ mkr)) = pk;
            }
            asm volatile("s_waitcnt lgkmcnt(0)" ::: "memory");
            GBAR();   // M2: P visible to all waves

            // ---- PV: wave w owns d = w*32 .. w*32+31 ----
            const unsigned char* vb = lds + 32768 + cur*16384;
            bf16x8 pa[4][2], vf[2][2];
            #pragma unroll
            for (int qtl=0;qtl<4;qtl++)
              #pragma unroll
              for (int ks=0;ks<2;ks++)
                pa[qtl][ks] = *(const bf16x8*)(lds + 65536 + (qtl*16 + r16)*128 + ((ks*64 + quad*16) ^ mkr));
            #pragma unroll
            for (int dt=0;dt<2;dt++)
              #pragma unroll
              for (int ks=0;ks<2;ks++)
                vf[dt][ks] = *(const bf16x8*)(vb + (w*32 + dt*16 + r16)*128 + ((ks*64 + quad*16) ^ mkr));
            __builtin_amdgcn_s_setprio(1);
            #pragma unroll
            for (int qtl=0;qtl<4;qtl++)
              #pragma unroll
              for (int dt=0;dt<2;dt++)
                #pragma unroll
                for (int ks=0;ks<2;ks++)
                  oacc[qtl][dt] = __builtin_amdgcn_mfma_f32_16x16x32_bf16(pa[qtl][ks], vf[dt][ks], oacc[qtl][dt], 0,0,0);
            __builtin_amdgcn_s_setprio(0);
            GBAR();   // E: all PV/P reads consumed before next stage overwrites cur
            cur ^= 1;
        }

        // ---- epilogue ----
        #pragma unroll
        for (int qtl=0;qtl<4;qtl++) {
            float dv = dsum[qtl];
            dv += __shfl_xor(dv, 16); dv += __shfl_xor(dv, 32);
            if (lane < 16) dsums[w*64 + qtl*16 + r16] = dv;
        }
        __syncthreads();
        float scl[4][4], pss[4][4];
        #pragma unroll
        for (int qtl=0;qtl<4;qtl++) {
            #pragma unroll
            for (int r=0;r<4;r++) {
                int nl = qtl*16 + quad*4 + r;
                float dv = dsums[nl] + dsums[64+nl] + dsums[128+nl] + dsums[192+nl];
                float nr = dnorm[hh*S_ + n0 + nl];
                float sc = nr / fmaxf(1.f, dv * nr);
                scl[qtl][r] = sc;
                float s2 = 0.f;
                #pragma unroll
                for (int dt=0;dt<2;dt++) { float t = oacc[qtl][dt][r]*sc; s2 += t*t; }
                s2 += __shfl_xor(s2,1); s2 += __shfl_xor(s2,2);
                s2 += __shfl_xor(s2,4); s2 += __shfl_xor(s2,8);
                pss[qtl][r] = s2;
            }
        }
        if (r16 == 0) {
            #pragma unroll
            for (int qtl=0;qtl<4;qtl++)
              #pragma unroll
              for (int r=0;r<4;r++)
                ssums[w*64 + qtl*16 + quad*4 + r] = pss[qtl][r];
        }
        __syncthreads();
        #pragma unroll
        for (int qtl=0;qtl<4;qtl++) {
            float rms[4];
            #pragma unroll
            for (int r=0;r<4;r++) {
                int nl = qtl*16 + quad*4 + r;
                float s2 = ssums[nl] + ssums[64+nl] + ssums[128+nl] + ssums[192+nl];
                rms[r] = rsqrtf(s2*(1.f/DK_) + 1e-6f);
            }
            #pragma unroll
            for (int dt=0;dt<2;dt++) {
                int d = w*32 + dt*16 + r16;
                float gg = gng[hh*DK_ + d];
                #pragma unroll
                for (int r=0;r<4;r++) {
                    int n = n0 + qtl*16 + quad*4 + r;
                    float gv = b2f(qk_base[(size_t)(b*S_ + n)*D2_ + 3072 + hh*DK_ + d]);
                    float sg = gv / (1.f + expf(-gv));
                    float ov = oacc[qtl][dt][r]*scl[qtl][r]*rms[r]*gg;
                    attnin[(size_t)(b*S_ + n)*D_ + hh*DK_ + d] = f2b(ov*sg);
                }
            }
        }
        __syncthreads();
    }
}

// ---------------- final LN (bf16 in) + regression head ----------------
__global__ __launch_bounds__(256) void head_out_k(const unsigned short* __restrict__ h, const float* __restrict__ s,
    const float* __restrict__ b, const float* __restrict__ wreg, const float* __restrict__ breg,
    float* __restrict__ out)
{
    __shared__ float red[4];
    int row = blockIdx.x, t = threadIdx.x;
    const unsigned short* xr = h + (size_t)row*D_;
    ushort4 u = ((const ushort4*)xr)[t];
    float v0=b2f(u.x), v1=b2f(u.y), v2=b2f(u.z), v3=b2f(u.w);
    float mu = bsum(v0+v1+v2+v3, red, t) * (1.f/D_);
    float d0=v0-mu, d1=v1-mu, d2=v2-mu, d3=v3-mu;
    float var = bsum(d0*d0+d1*d1+d2*d2+d3*d3, red, t) * (1.f/D_);
    float inv = rsqrtf(var + 1e-6f);
    int c = t*4;
    float dot = (d0*inv*s[c+0]+b[c+0])*wreg[c+0] + (d1*inv*s[c+1]+b[c+1])*wreg[c+1]
              + (d2*inv*s[c+2]+b[c+2])*wreg[c+2] + (d3*inv*s[c+3]+b[c+3])*wreg[c+3];
    dot = bsum(dot, red, t);
    if (t == 0) out[row] = 1.1f / (1.f + expf(-(dot + breg[0]))) - 0.05f;
}

extern "C" void kernel_launch(void* const* d_in, const int* in_sizes, int n_in,
                              void* d_out, int out_size, void* d_ws, size_t ws_size,
                              hipStream_t stream)
{
    (void)in_sizes; (void)n_in; (void)out_size; (void)ws_size;
    const float* x    = (const float*)d_in[0];
    const float* W_in = (const float*)d_in[1];
    const float* b_in = (const float*)d_in[2];
    const float* Wq   = (const float*)d_in[3];
    const float* Wk   = (const float*)d_in[4];
    const float* Wv   = (const float*)d_in[5];
    const float* Wg   = (const float*)d_in[6];
    const float* Wo   = (const float*)d_in[7];
    const float* gn_g = (const float*)d_in[8];
    const float* ln1s = (const float*)d_in[9];
    const float* ln1b = (const float*)d_in[10];
    const float* W1   = (const float*)d_in[11];
    const float* b1   = (const float*)d_in[12];
    const float* W2   = (const float*)d_in[13];
    const float* b2   = (const float*)d_in[14];
    const float* ln2s = (const float*)d_in[15];
    const float* ln2b = (const float*)d_in[16];
    const float* lnfs = (const float*)d_in[17];
    const float* lnfb = (const float*)d_in[18];
    const float* Wreg = (const float*)d_in[19];
    const float* breg = (const float*)d_in[20];

    char* ws = (char*)d_ws;
    size_t off = 0;
    auto alloc = [&](size_t bytes) { char* p = ws + off; off += (bytes + 255) & ~(size_t)255; return p; };

    const size_t DD = (size_t)D_*D_;
    unsigned short* wqkvgT = (unsigned short*)alloc((size_t)L_*4*DD*2);   // [l][4D][D]
    unsigned short* woT  = (unsigned short*)alloc((size_t)L_*DD*2);
    unsigned short* w1T  = (unsigned short*)alloc((size_t)L_*D_*F_*2);
    unsigned short* w2T  = (unsigned short*)alloc((size_t)L_*D_*F_*2);
    unsigned short* winT = (unsigned short*)alloc((size_t)D_*IN_*2);
    unsigned short* x_bf = (unsigned short*)alloc((size_t)BS_*IN_*2);
    unsigned short* hbuf = (unsigned short*)alloc((size_t)BS_*D_*2);    // bf16 residual stream
    unsigned short* y_bf = (unsigned short*)alloc((size_t)BS_*D_*2);
    unsigned short* qkvg = (unsigned short*)alloc((size_t)BS_*D2_*2);
    unsigned short* vTb  = (unsigned short*)alloc((size_t)BS_*D_*2);
    float*          cost = (float*)alloc((size_t)S_*DK_*4);
    float*          sint = (float*)alloc((size_t)S_*DK_*4);
    float*          dnrm = (float*)alloc((size_t)H_*S_*4);
    unsigned short* attn = y_bf;   // alias: y_bf dead after qkvg GEMM, rewritten by ln2 later
    unsigned short* midb = qkvg;   // alias: qkvg dead after retention

    dim3 tb(32, 8);

    // prep
    f32_to_bf16_k<<<(BS_*IN_)/256, 256, 0, stream>>>(x, x_bf, BS_*IN_);
    transpose_w_k<<<dim3(32,32,L_), tb, 0, stream>>>(Wq, wqkvgT + 0*DD, D_, D_, 4*DD);
    transpose_w_k<<<dim3(32,32,L_), tb, 0, stream>>>(Wk, wqkvgT + 1*DD, D_, D_, 4*DD);
    transpose_w_k<<<dim3(32,32,L_), tb, 0, stream>>>(Wv, wqkvgT + 2*DD, D_, D_, 4*DD);
    transpose_w_k<<<dim3(32,32,L_), tb, 0, stream>>>(Wg, wqkvgT + 3*DD, D_, D_, 4*DD);
    transpose_w_k<<<dim3(32,32,L_), tb, 0, stream>>>(Wo, woT, D_, D_, DD);
    transpose_w_k<<<dim3(64,32,L_), tb, 0, stream>>>(W1, w1T, D_, F_, (size_t)D_*F_);
    transpose_w_k<<<dim3(32,64,L_), tb, 0, stream>>>(W2, w2T, F_, D_, (size_t)D_*F_);
    transpose_w_k<<<dim3(32, 4, 1), tb, 0, stream>>>(W_in, winT, IN_, D_, (size_t)D_*IN_);
    build_sincos_k<<<(S_*64)/256, 256, 0, stream>>>(cost, sint);
    build_dnorm_k<<<(H_*S_)/256, 256, 0, stream>>>(dnrm);

    // input projection: h = x @ W_in + b_in   (K=128 -> NT=2)
    gemm6<0,128,128><<<dim3(D_/128, BS_/128), 512, 0, stream>>>(x_bf, winT, b_in, hbuf, BS_, D_, IN_);

    for (int l = 0; l < L_; ++l) {
        ln_to_bf16_k<<<BS_, 256, 0, stream>>>(hbuf, ln1s + l*D_, ln1b + l*D_, y_bf);
        gemm6<2,256,256><<<dim3(D2_/256, BS_/256), 512, 0, stream>>>(y_bf, wqkvgT + (size_t)l*4*DD, nullptr, qkvg, BS_, D2_, D_);
        rope_vt_k<<<dim3(S_/32, DK_/32, B_*H_), tb, 0, stream>>>(qkvg, vTb, cost, sint);
        retention_k<<<dim3(16, B_*H_), 256, 0, stream>>>(qkvg, vTb, dnrm, gn_g + l*D_, attn);
        gemm6<1,128,128><<<dim3(D_/128, BS_/128), 512, 0, stream>>>(attn, woT + (size_t)l*DD, nullptr, hbuf, BS_, D_, D_);
        ln_to_bf16_k<<<BS_, 256, 0, stream>>>(hbuf, ln2s + l*D_, ln2b + l*D_, y_bf);
        gemm6<3,256,256><<<dim3(F_/256, BS_/256), 512, 0, stream>>>(y_bf, w1T + (size_t)l*D_*F_, b1 + l*F_, midb, BS_, F_, D_);
        gemm6<1,128,128><<<dim3(D_/128, BS_/128), 512, 0, stream>>>(midb, w2T + (size_t)l*D_*F_, b2 + l*D_, hbuf, BS_, D_, F_);
    }

    head_out_k<<<BS_, 256, 0, stream>>>(hbuf, lnfs, lnfb, Wreg, breg, (float*)d_out);
}

// Round 18
// 1803.505 us; speedup vs baseline: 1.0180x; 1.0180x over previous
//
#include <hip/hip_runtime.h>

#define L_ 6
#define D_ 1024
#define H_ 8
#define F_ 2048
#define B_ 4
#define S_ 2048
#define IN_ 128
#define DK_ 128
#define BS_ (B_*S_)
#define D2_ 4096     // fused qkvg row stride

typedef short bf16x8 __attribute__((ext_vector_type(8)));
typedef float f32x4 __attribute__((ext_vector_type(4)));

__device__ inline float b2f(unsigned short u){ union{unsigned int i; float f;} v; v.i = ((unsigned int)u)<<16; return v.f; }
__device__ inline unsigned short f2b(float f){ union{unsigned int i; float f;} v; v.f = f; unsigned int r = v.i + 0x7FFFu + ((v.i>>16)&1u); return (unsigned short)(r>>16); }
__device__ inline unsigned int cvtpk(float lo, float hi){
    unsigned int r; asm("v_cvt_pk_bf16_f32 %0, %1, %2" : "=v"(r) : "v"(lo), "v"(hi)); return r;
}

__device__ inline void gld16(const void* g, void* l) {
    __builtin_amdgcn_global_load_lds((const __attribute__((address_space(1))) unsigned int*)g,
                                     (__attribute__((address_space(3))) unsigned int*)l, 16, 0, 0);
}

#define GBAR() do{ asm volatile("" ::: "memory"); __builtin_amdgcn_s_barrier(); asm volatile("" ::: "memory"); }while(0)

// ---------------- elementwise convert ----------------
__global__ void f32_to_bf16_k(const float* __restrict__ in, unsigned short* __restrict__ out, int n)
{
    int i = blockIdx.x*256 + threadIdx.x;
    if (i < n) out[i] = f2b(in[i]);
}

// ---------------- weight transpose-convert: out[z*ostride + c*R + r] = in[z][r][c] ----------------
__global__ void transpose_w_k(const float* __restrict__ in, unsigned short* __restrict__ out, int R, int C, size_t ostride)
{
    __shared__ float tile[32][33];
    int z = blockIdx.z;
    const float* pi = in + (size_t)z*R*C;
    unsigned short* po = out + (size_t)z*ostride;
    int c0 = blockIdx.x*32, r0 = blockIdx.y*32;
    int tx = threadIdx.x, ty = threadIdx.y;
    #pragma unroll
    for (int i=0;i<4;i++) tile[ty+i*8][tx] = pi[(size_t)(r0+ty+i*8)*C + c0+tx];
    __syncthreads();
    #pragma unroll
    for (int i=0;i<4;i++) po[(size_t)(c0+ty+i*8)*R + r0+tx] = f2b(tile[tx][ty+i*8]);
}

// ---------------- fused RoPE (q,k in-place) + v transpose to (B,H,DK,S) ----------------
// grid (S/32, DK/32, B*H), block (32,8)
__global__ void rope_vt_k(unsigned short* __restrict__ qkvg, unsigned short* __restrict__ vT,
                          const float* __restrict__ cost, const float* __restrict__ sint)
{
    __shared__ unsigned short tile[32][33];
    int z = blockIdx.z;             // b*H + h
    int b = z >> 3, hh = z & 7;
    int s0 = blockIdx.x*32, d0 = blockIdx.y*32;
    int tx = threadIdx.x, ty = threadIdx.y;
    const unsigned short* vb = qkvg + 2048;
    #pragma unroll
    for (int i=0;i<4;i++) tile[ty+i*8][tx] = vb[(size_t)(b*S_ + s0+ty+i*8)*D2_ + hh*DK_ + d0+tx];

    // rope: 512 (row, pair) items over 256 threads
    int t = ty*32 + tx;
    #pragma unroll
    for (int it=0; it<2; ++it) {
        int idx = it*256 + t;
        int row = idx >> 4;            // 0..31
        int pr  = idx & 15;            // pair in 0..15
        int s  = s0 + row;
        int dk = d0 + pr*2;
        float c0 = cost[s*DK_ + dk],   sn0 = sint[s*DK_ + dk];
        float c1 = cost[s*DK_ + dk+1], sn1 = sint[s*DK_ + dk+1];
        size_t off = (size_t)(b*S_ + s)*D2_ + hh*DK_ + dk;
        unsigned int qu = *(unsigned int*)(qkvg + off);
        float q0 = b2f((unsigned short)(qu & 0xffffu)), q1 = b2f((unsigned short)(qu >> 16));
        float r0 = q0*c0 - q1*sn0;
        float r1 = q1*c1 + q0*sn1;
        *(unsigned int*)(qkvg + off) = (unsigned int)f2b(r0) | ((unsigned int)f2b(r1) << 16);
        const float sc = 0.08838834764831845f;
        unsigned int ku = *(unsigned int*)(qkvg + off + 1024);
        float k0 = b2f((unsigned short)(ku & 0xffffu))*sc, k1 = b2f((unsigned short)(ku >> 16))*sc;
        float t0 = k0*c0 - k1*sn0;
        float t1 = k1*c1 + k0*sn1;
        *(unsigned int*)(qkvg + off + 1024) = (unsigned int)f2b(t0) | ((unsigned int)f2b(t1) << 16);
    }

    __syncthreads();
    #pragma unroll
    for (int i=0;i<4;i++) vT[((size_t)z*DK_ + d0+ty+i*8)*S_ + s0+tx] = tile[tx][ty+i*8];
}

// ---------------- tables ----------------
__global__ void build_sincos_k(float* __restrict__ cost, float* __restrict__ sint)
{
    int id = blockIdx.x*256 + threadIdx.x;     // S*64
    int s = id >> 6, i = id & 63;
    float ang = powf(10000.f, -(float)i/63.f);
    float a = (float)s * ang;
    float sv = sinf(a), cv = cosf(a);
    sint[s*DK_ + 2*i] = sv; sint[s*DK_ + 2*i+1] = sv;
    cost[s*DK_ + 2*i] = cv; cost[s*DK_ + 2*i+1] = cv;
}

__global__ void build_dnorm_k(float* __restrict__ dnorm)
{
    int id = blockIdx.x*256 + threadIdx.x;     // H*S
    int h = id >> 11, n = id & (S_-1);
    double g = 1.0 - exp2((double)(-5 - h));
    double sum = (1.0 - exp(((double)(n+1))*log(g))) / (1.0 - g);
    dnorm[id] = (float)(1.0/sqrt(sum));
}

// ---------------- block reduce helper (256 threads) ----------------
__device__ inline float bsum(float v, float* red, int t)
{
    #pragma unroll
    for (int m=32; m; m>>=1) v += __shfl_xor(v, m);
    __syncthreads();
    if ((t & 63) == 0) red[t>>6] = v;
    __syncthreads();
    return red[0]+red[1]+red[2]+red[3];
}

// ---------------- layernorm (bf16 in) -> bf16 ----------------
__global__ __launch_bounds__(256) void ln_to_bf16_k(const unsigned short* __restrict__ x, const float* __restrict__ s,
                                                    const float* __restrict__ b, unsigned short* __restrict__ y)
{
    __shared__ float red[4];
    int row = blockIdx.x, t = threadIdx.x;
    const unsigned short* xr = x + (size_t)row * D_;
    ushort4 u = ((const ushort4*)xr)[t];
    float v0=b2f(u.x), v1=b2f(u.y), v2=b2f(u.z), v3=b2f(u.w);
    float mu = bsum(v0+v1+v2+v3, red, t) * (1.f/D_);
    float d0=v0-mu, d1=v1-mu, d2=v2-mu, d3=v3-mu;
    float var = bsum(d0*d0+d1*d1+d2*d2+d3*d3, red, t) * (1.f/D_);
    float inv = rsqrtf(var + 1e-6f);
    int c = t*4;
    float o0 = d0*inv*s[c+0] + b[c+0];
    float o1 = d1*inv*s[c+1] + b[c+1];
    float o2 = d2*inv*s[c+2] + b[c+2];
    float o3 = d3*inv*s[c+3] + b[c+3];
    unsigned long long pk = (unsigned long long)f2b(o0) | ((unsigned long long)f2b(o1)<<16)
                          | ((unsigned long long)f2b(o2)<<32) | ((unsigned long long)f2b(o3)<<48);
    *(unsigned long long*)(y + (size_t)row*D_ + c) = pk;
}

// ============ GEMM v10 hybrid: BMxBN tile, BK=64, 2-buffer LDS ============
// C[M,N] = A[M,K] @ Bt[N,K]^T, 512 threads, 8 waves (2M x 4N)
// BN=256: per-kk single phase, staggered half-batch staging, counted vmcnt(4). 4 barriers/tile.
// BN=128 (round-13 schedule): full batch(t+1) at kk0, vmcnt(2Sa) kk0-end / vmcnt(Sa) kk1-end.
// MODE 0: bias+store bf16   1: bf16 RMW accumulate (+bias)   2: store bf16   3: bias+gelu -> bf16
template<int MODE, int BM, int BN>
__global__ __launch_bounds__(512, 2)
void gemm6(const unsigned short* __restrict__ A,
           const unsigned short* __restrict__ Bt,
           const float* __restrict__ bias,
           void* __restrict__ Cv,
           int M, int N, int K)
{
    constexpr int IR   = BM/2/16;         // 8 or 4
    constexpr int JR   = BN/64;           // 4 or 2
    constexpr int ASUB = BM*64;           // bytes per A K-subtile
    constexpr int BSUB = BN*64;
    constexpr int BUFSZ= 2*ASUB + 2*BSUB;
    constexpr int AP   = BM/128;          // gld16 passes per subtile
    constexpr int BP   = BN/128;
    constexpr int Sa   = AP + BP;         // gld16 per thread per K-subtile (kk)
    __shared__ unsigned char lds[2*BUFSZ];

    const int tid = threadIdx.x, lane = tid & 63, w = tid >> 6;
    const int r16 = lane & 15, quad = (lane >> 4) & 3;
    const int wm = w >> 2, wn = w & 3;

    // XCD-aware bijective block swizzle (grid % 8 == 0 in all our launches)
    const int nwg = (int)(gridDim.x * gridDim.y);
    int bid = (int)(blockIdx.y * gridDim.x + blockIdx.x);
    if ((nwg & 7) == 0) bid = (bid & 7) * (nwg >> 3) + (bid >> 3);
    const int m0 = (bid / (int)gridDim.x) * BM;
    const int n0 = (bid % (int)gridDim.x) * BN;

    // staging: thread -> (row = tid>>2, chunk = tid&3); source chunk inverse-swizzled
    const int srow = tid >> 2;
    const int schk = (tid & 3) ^ ((tid >> 3) & 3);
    const unsigned short* gA = A  + (size_t)(m0 + srow) * K + schk*8;
    const unsigned short* gB = Bt + (size_t)(n0 + srow) * K + schk*8;

    // swizzled read chunk (row bases multiples of 16 -> (row>>1)&3 == (r16>>1)&3)
    const int rchk = (quad ^ ((r16 >> 1) & 3)) * 16;
    const int aoff = (wm*(BM/2) + r16)*64 + rchk;
    const int boff = (wn*(BN/4) + r16)*64 + rchk;

    f32x4 acc[IR][JR];
    #pragma unroll
    for (int i=0;i<IR;i++)
      #pragma unroll
      for (int j=0;j<JR;j++) acc[i][j] = (f32x4){0.f,0.f,0.f,0.f};

    const int NT = K >> 6;   // 64-K tiles

    auto stageA = [&](int t, int kk){
        unsigned char* dst = lds + (t&1)*BUFSZ + kk*ASUB;
        const unsigned short* src = gA + (size_t)t*64 + kk*32;
        #pragma unroll
        for (int p=0;p<AP;p++)
            gld16(src + (size_t)(p*128)*K, dst + p*8192 + tid*16);
    };
    auto stageB = [&](int t, int kk){
        unsigned char* dst = lds + (t&1)*BUFSZ + 2*ASUB + kk*BSUB;
        const unsigned short* src = gB + (size_t)t*64 + kk*32;
        #pragma unroll
        for (int p=0;p<BP;p++)
            gld16(src + (size_t)(p*128)*K, dst + p*8192 + tid*16);
    };

    #define WAIT_N(nn) asm volatile("s_waitcnt vmcnt(" #nn ")" ::: "memory")
    #define WAIT_SA()  do{ if constexpr (Sa==4) WAIT_N(4); else WAIT_N(2); }while(0)
    #define WAIT_2SA() do{ if constexpr (Sa==4) WAIT_N(8); else WAIT_N(4); }while(0)

    // prologue: tile 0 staged (kk0 then kk1); land kk0 half, leave kk1 in flight
    stageA(0,0); stageB(0,0); stageA(0,1); stageB(0,1);
    WAIT_SA();
    GBAR();

    for (int t = 0; t < NT; ++t) {
        const unsigned char* cb = lds + (t&1)*BUFSZ;
        const bool pre = (t+1 < NT);

        if constexpr (BN == 256) {
            // ======== per-kk single phase, staggered staging, counted vmcnt(4) ========
            #pragma unroll
            for (int kk = 0; kk < 2; ++kk) {
                const unsigned char* ak = cb + kk*ASUB;
                const unsigned char* bk = cb + 2*ASUB + kk*BSUB;
                bf16x8 af[8], bg[JR];
                #pragma unroll
                for (int i=0;i<8;i++) af[i] = *(const bf16x8*)(ak + aoff + i*1024);
                #pragma unroll
                for (int j=0;j<JR;j++) bg[j] = *(const bf16x8*)(bk + boff + j*1024);
                if (pre) { stageA(t+1, kk); stageB(t+1, kk); }
                GBAR();
                asm volatile("s_waitcnt lgkmcnt(0)" ::: "memory");
                __builtin_amdgcn_s_setprio(1);
                #pragma unroll
                for (int i=0;i<8;i++)
                  #pragma unroll
                  for (int j=0;j<JR;j++)
                    acc[i][j] = __builtin_amdgcn_mfma_f32_16x16x32_bf16(af[i], bg[j], acc[i][j], 0,0,0);
                __builtin_amdgcn_s_setprio(0);
                if (pre) { WAIT_SA(); }
                else     { WAIT_N(0); }
                GBAR();
            }
        } else {
            // ======== round-13 schedule: full batch at kk0, deep counted waits ========
            const unsigned char* ak0 = cb;
            const unsigned char* bk0 = cb + 2*ASUB;
            const unsigned char* ak1 = cb + ASUB;
            const unsigned char* bk1 = cb + 2*ASUB + BSUB;
            // ---- kk0 single phase ----
            bf16x8 af[IR], bg[JR];
            #pragma unroll
            for (int i=0;i<IR;i++) af[i] = *(const bf16x8*)(ak0 + aoff + i*1024);
            #pragma unroll
            for (int j=0;j<JR;j++) bg[j] = *(const bf16x8*)(bk0 + boff + j*1024);
            if (pre) { stageA(t+1,0); stageB(t+1,0); stageA(t+1,1); stageB(t+1,1); }
            GBAR();
            asm volatile("s_waitcnt lgkmcnt(0)" ::: "memory");
            __builtin_amdgcn_s_setprio(1);
            #pragma unroll
            for (int i=0;i<IR;i++)
              #pragma unroll
              for (int j=0;j<JR;j++)
                acc[i][j] = __builtin_amdgcn_mfma_f32_16x16x32_bf16(af[i], bg[j], acc[i][j], 0,0,0);
            __builtin_amdgcn_s_setprio(0);
            if (pre) { WAIT_2SA(); } else { WAIT_N(0); }
            GBAR();
            // ---- kk1 single phase ----
            #pragma unroll
            for (int i=0;i<IR;i++) af[i] = *(const bf16x8*)(ak1 + aoff + i*1024);
            #pragma unroll
            for (int j=0;j<JR;j++) bg[j] = *(const bf16x8*)(bk1 + boff + j*1024);
            GBAR();
            asm volatile("s_waitcnt lgkmcnt(0)" ::: "memory");
            __builtin_amdgcn_s_setprio(1);
            #pragma unroll
            for (int i=0;i<IR;i++)
              #pragma unroll
              for (int j=0;j<JR;j++)
                acc[i][j] = __builtin_amdgcn_mfma_f32_16x16x32_bf16(af[i], bg[j], acc[i][j], 0,0,0);
            __builtin_amdgcn_s_setprio(0);
            if (pre) { WAIT_SA(); }
            GBAR();
        }
    }
    #undef WAIT_N
    #undef WAIT_SA
    #undef WAIT_2SA

    // epilogue: (i,r)-outer, j-inner -> contiguous row segments in adjacent stores
    unsigned short* Cb = (unsigned short*)Cv;
    float bvs[JR];
    #pragma unroll
    for (int j=0;j<JR;j++) bvs[j] = bias ? bias[n0 + wn*(BN/4) + j*16 + r16] : 0.f;
    #pragma unroll
    for (int i=0;i<IR;i++) {
      #pragma unroll
      for (int r=0;r<4;r++) {
        const size_t crow = (size_t)(m0 + wm*(BM/2) + i*16 + quad*4 + r);
        #pragma unroll
        for (int j=0;j<JR;j++) {
          const int ccol = n0 + wn*(BN/4) + j*16 + r16;
          float v = acc[i][j][r];
          if (MODE == 0) { Cb[crow*N + ccol] = f2b(v + bvs[j]); }
          else if (MODE == 1) { Cb[crow*N + ccol] = f2b(b2f(Cb[crow*N + ccol]) + v + bvs[j]); }
          else if (MODE == 2) { Cb[crow*N + ccol] = f2b(v); }
          else {
            v += bvs[j];
            float t3 = tanhf(0.7978845608028654f*(v + 0.044715f*v*v*v));
            Cb[crow*N + ccol] = f2b(0.5f*v*(1.f + t3));
          }
        }
      }
    }
}

// ====== retention: 64-q-row tiles, diagonal pair per block, wave-split K (QK) / d (PV) ======
// XCD-locality remap: linear block L -> XCD k=L%8 owns bh in [4k,4k+4) so each XCD's
// K/V working set = 4 heads x 1MB = 4MB = its L2. P rows: 128B stride + chunk XOR (conflict-free).
// LDS: K dbuf 2x16KB @0; V dbuf 2x16KB @32768; P[64][64] 8KB @65536; dsums @73728; ssums @74752
__global__ __launch_bounds__(256, 2) void retention_k(const unsigned short* __restrict__ qk_base,
    const unsigned short* __restrict__ vT, const float* __restrict__ dnorm,
    const float* __restrict__ gng, unsigned short* __restrict__ attnin)
{
    __shared__ __align__(16) unsigned char lds[75776];
    const int Lf = (int)(blockIdx.y * gridDim.x + blockIdx.x);
    const int kx = Lf & 7, mm = Lf >> 3;
    const int bh = 4*kx + (mm >> 4);     // XCD kx serves bh 4kx..4kx+3
    const int pr = mm & 15;              // 0..15 : pair (31-pr, pr)
    const int b = bh >> 3, hh = bh & 7;
    const int tid = threadIdx.x, lane = tid & 63, w = tid >> 6;
    const int r16 = lane & 15, quad = lane >> 4;

    const float l2g = log2f(1.f - exp2f(-5.f - (float)hh));
    const int ithr = (int)(45.f / (-l2g));
    const unsigned int mkr = (r16 & 7) << 4;

    // staging sources (pre-swizzled global, linear LDS dest)
    const int mk2  = ((tid >> 4) & 7) << 4;
    const int mkv2 = ((tid >> 3) & 7) << 4;
    const unsigned short* ksrc = qk_base + 1024 + ((size_t)(b*S_) + (tid>>4))*D2_ + hh*DK_
                                + ((((tid&15)*16) ^ mk2) >> 1);
    const unsigned short* vsrc = vT + ((size_t)bh*DK_ + (tid>>3))*S_ + ((((tid&7)*16) ^ mkv2) >> 1);

    // key-side decay factor, loop-invariant: Aarr[r] = 2^(l2g*(63 - m_loc)), m_loc = w*16+quad*4+r
    float Aarr[4];
    #pragma unroll
    for (int r=0;r<4;r++) Aarr[r] = exp2f(l2g * (float)(63 - (w*16 + quad*4 + r)));

    float* dsums = (float*)(lds + 73728);
    float* ssums = (float*)(lds + 74752);

    auto stage = [&](int c2, int kt2){
        const unsigned short* s0 = ksrc + (size_t)kt2*64*D2_;
        #pragma unroll
        for (int i=0;i<4;i++)
            gld16(s0 + (size_t)i*16*D2_, lds + c2*16384 + i*4096 + w*1024);
        const unsigned short* s1 = vsrc + kt2*64;
        #pragma unroll
        for (int j=0;j<4;j++)
            gld16(s1 + (size_t)j*32*S_, lds + 32768 + c2*16384 + j*4096 + w*1024);
    };

    int cur = 0;

    #pragma unroll 1
    for (int seg = 0; seg < 2; ++seg) {
        const int qt = seg ? pr : (31 - pr);
        const int n0 = qt * 64;
        const int kt_start = max(0, (n0 - ithr) >> 6);

        // Q fragments (B-operand, all 64 q-cols): qf[qtile][c]
        bf16x8 qf[4][4];
        const unsigned short* qptr = qk_base + ((size_t)(b*S_ + n0 + r16))*D2_ + hh*DK_;
        #pragma unroll
        for (int qtl=0;qtl<4;qtl++)
          #pragma unroll
          for (int c=0;c<4;c++) qf[qtl][c] = *(const bf16x8*)(qptr + qtl*16*D2_ + c*32 + quad*8);

        f32x4 oacc[4][2];   // [qtile][dtile]; row=q(quad*4+r), col=d(w*32+dtile*16+r16)
        #pragma unroll
        for (int qtl=0;qtl<4;qtl++)
          #pragma unroll
          for (int dt=0;dt<2;dt++) oacc[qtl][dt] = (f32x4){0.f,0.f,0.f,0.f};
        float dsum[4] = {0.f,0.f,0.f,0.f};

        stage(cur, kt_start);

        #pragma unroll 1
        for (int kt = kt_start; kt <= qt; ++kt) {
            if (kt < qt) { stage(cur^1, kt+1); asm volatile("s_waitcnt vmcnt(8)" ::: "memory"); }
            else         { asm volatile("s_waitcnt vmcnt(0)" ::: "memory"); }
            GBAR();   // M1: K/V[cur] fully staged on all waves

            // ---- QK: wave w owns keys w*16..w*16+15 ----
            const unsigned char* kb = lds + cur*16384;
            bf16x8 kf[4];
            #pragma unroll
            for (int c=0;c<4;c++)
                kf[c] = *(const bf16x8*)(kb + (w*16 + r16)*256 + ((c*64 + quad*16) ^ mkr));
            f32x4 sf[4];
            #pragma unroll
            for (int qtl=0;qtl<4;qtl++) sf[qtl] = (f32x4){0.f,0.f,0.f,0.f};
            __builtin_amdgcn_s_setprio(1);
            #pragma unroll
            for (int c=0;c<4;c++)
              #pragma unroll
              for (int qtl=0;qtl<4;qtl++)
                sf[qtl] = __builtin_amdgcn_mfma_f32_16x16x32_bf16(kf[c], qf[qtl][c], sf[qtl], 0,0,0);
            __builtin_amdgcn_s_setprio(0);

            // ---- decay + mask + P write (P[q][k], 128B row stride, swizzled) ----
            const bool diag = (kt == qt);
            #pragma unroll
            for (int qtl=0;qtl<4;qtl++) {
                float Bq = exp2f(l2g * (float)(n0 + qtl*16 + r16 - kt*64 - 63));
                float pv[4];
                #pragma unroll
                for (int r=0;r<4;r++) {
                    float p = sf[qtl][r] * Aarr[r] * Bq;
                    if (diag && (w*16 + quad*4 + r > qtl*16 + r16)) p = 0.f;
                    dsum[qtl] += fabsf(p);
                    pv[r] = p;
                }
                unsigned long long pk = (unsigned long long)cvtpk(pv[0], pv[1])
                                      | ((unsigned long long)cvtpk(pv[2], pv[3]) << 32);
                *(unsigned long long*)(lds + 65536 + (qtl*16 + r16)*128 + ((w*32 + quad*8) ^ mkr)) = pk;
            }
            asm volatile("s_waitcnt lgkmcnt(0)" ::: "memory");
            GBAR();   // M2: P visible to all waves

            // ---- PV: wave w owns d = w*32 .. w*32+31 ----
            const unsigned char* vb = lds + 32768 + cur*16384;
            bf16x8 pa[4][2], vf[2][2];
            #pragma unroll
            for (int qtl=0;qtl<4;qtl++)
              #pragma unroll
              for (int ks=0;ks<2;ks++)
                pa[qtl][ks] = *(const bf16x8*)(lds + 65536 + (qtl*16 + r16)*128 + ((ks*64 + quad*16) ^ mkr));
            #pragma unroll
            for (int dt=0;dt<2;dt++)
              #pragma unroll
              for (int ks=0;ks<2;ks++)
                vf[dt][ks] = *(const bf16x8*)(vb + (w*32 + dt*16 + r16)*128 + ((ks*64 + quad*16) ^ mkr));
            __builtin_amdgcn_s_setprio(1);
            #pragma unroll
            for (int qtl=0;qtl<4;qtl++)
              #pragma unroll
              for (int dt=0;dt<2;dt++)
                #pragma unroll
                for (int ks=0;ks<2;ks++)
                  oacc[qtl][dt] = __builtin_amdgcn_mfma_f32_16x16x32_bf16(pa[qtl][ks], vf[dt][ks], oacc[qtl][dt], 0,0,0);
            __builtin_amdgcn_s_setprio(0);
            GBAR();   // E: all PV/P reads consumed before next stage overwrites cur
            cur ^= 1;
        }

        // ---- epilogue ----
        #pragma unroll
        for (int qtl=0;qtl<4;qtl++) {
            float dv = dsum[qtl];
            dv += __shfl_xor(dv, 16); dv += __shfl_xor(dv, 32);
            if (lane < 16) dsums[w*64 + qtl*16 + r16] = dv;
        }
        __syncthreads();
        float scl[4][4], pss[4][4];
        #pragma unroll
        for (int qtl=0;qtl<4;qtl++) {
            #pragma unroll
            for (int r=0;r<4;r++) {
                int nl = qtl*16 + quad*4 + r;
                float dv = dsums[nl] + dsums[64+nl] + dsums[128+nl] + dsums[192+nl];
                float nr = dnorm[hh*S_ + n0 + nl];
                float sc = nr / fmaxf(1.f, dv * nr);
                scl[qtl][r] = sc;
                float s2 = 0.f;
                #pragma unroll
                for (int dt=0;dt<2;dt++) { float t = oacc[qtl][dt][r]*sc; s2 += t*t; }
                s2 += __shfl_xor(s2,1); s2 += __shfl_xor(s2,2);
                s2 += __shfl_xor(s2,4); s2 += __shfl_xor(s2,8);
                pss[qtl][r] = s2;
            }
        }
        if (r16 == 0) {
            #pragma unroll
            for (int qtl=0;qtl<4;qtl++)
              #pragma unroll
              for (int r=0;r<4;r++)
                ssums[w*64 + qtl*16 + quad*4 + r] = pss[qtl][r];
        }
        __syncthreads();
        #pragma unroll
        for (int qtl=0;qtl<4;qtl++) {
            float rms[4];
            #pragma unroll
            for (int r=0;r<4;r++) {
                int nl = qtl*16 + quad*4 + r;
                float s2 = ssums[nl] + ssums[64+nl] + ssums[128+nl] + ssums[192+nl];
                rms[r] = rsqrtf(s2*(1.f/DK_) + 1e-6f);
            }
            #pragma unroll
            for (int dt=0;dt<2;dt++) {
                int d = w*32 + dt*16 + r16;
                float gg = gng[hh*DK_ + d];
                #pragma unroll
                for (int r=0;r<4;r++) {
                    int n = n0 + qtl*16 + quad*4 + r;
                    float gv = b2f(qk_base[(size_t)(b*S_ + n)*D2_ + 3072 + hh*DK_ + d]);
                    float sg = gv / (1.f + expf(-gv));
                    float ov = oacc[qtl][dt][r]*scl[qtl][r]*rms[r]*gg;
                    attnin[(size_t)(b*S_ + n)*D_ + hh*DK_ + d] = f2b(ov*sg);
                }
            }
        }
        __syncthreads();
    }
}

// ---------------- final LN (bf16 in) + regression head ----------------
__global__ __launch_bounds__(256) void head_out_k(const unsigned short* __restrict__ h, const float* __restrict__ s,
    const float* __restrict__ b, const float* __restrict__ wreg, const float* __restrict__ breg,
    float* __restrict__ out)
{
    __shared__ float red[4];
    int row = blockIdx.x, t = threadIdx.x;
    const unsigned short* xr = h + (size_t)row*D_;
    ushort4 u = ((const ushort4*)xr)[t];
    float v0=b2f(u.x), v1=b2f(u.y), v2=b2f(u.z), v3=b2f(u.w);
    float mu = bsum(v0+v1+v2+v3, red, t) * (1.f/D_);
    float d0=v0-mu, d1=v1-mu, d2=v2-mu, d3=v3-mu;
    float var = bsum(d0*d0+d1*d1+d2*d2+d3*d3, red, t) * (1.f/D_);
    float inv = rsqrtf(var + 1e-6f);
    int c = t*4;
    float dot = (d0*inv*s[c+0]+b[c+0])*wreg[c+0] + (d1*inv*s[c+1]+b[c+1])*wreg[c+1]
              + (d2*inv*s[c+2]+b[c+2])*wreg[c+2] + (d3*inv*s[c+3]+b[c+3])*wreg[c+3];
    dot = bsum(dot, red, t);
    if (t == 0) out[row] = 1.1f / (1.f + expf(-(dot + breg[0]))) - 0.05f;
}

extern "C" void kernel_launch(void* const* d_in, const int* in_sizes, int n_in,
                              void* d_out, int out_size, void* d_ws, size_t ws_size,
                              hipStream_t stream)
{
    (void)in_sizes; (void)n_in; (void)out_size; (void)ws_size;
    const float* x    = (const float*)d_in[0];
    const float* W_in = (const float*)d_in[1];
    const float* b_in = (const float*)d_in[2];
    const float* Wq   = (const float*)d_in[3];
    const float* Wk   = (const float*)d_in[4];
    const float* Wv   = (const float*)d_in[5];
    const float* Wg   = (const float*)d_in[6];
    const float* Wo   = (const float*)d_in[7];
    const float* gn_g = (const float*)d_in[8];
    const float* ln1s = (const float*)d_in[9];
    const float* ln1b = (const float*)d_in[10];
    const float* W1   = (const float*)d_in[11];
    const float* b1   = (const float*)d_in[12];
    const float* W2   = (const float*)d_in[13];
    const float* b2   = (const float*)d_in[14];
    const float* ln2s = (const float*)d_in[15];
    const float* ln2b = (const float*)d_in[16];
    const float* lnfs = (const float*)d_in[17];
    const float* lnfb = (const float*)d_in[18];
    const float* Wreg = (const float*)d_in[19];
    const float* breg = (const float*)d_in[20];

    char* ws = (char*)d_ws;
    size_t off = 0;
    auto alloc = [&](size_t bytes) { char* p = ws + off; off += (bytes + 255) & ~(size_t)255; return p; };

    const size_t DD = (size_t)D_*D_;
    unsigned short* wqkvgT = (unsigned short*)alloc((size_t)L_*4*DD*2);   // [l][4D][D]
    unsigned short* woT  = (unsigned short*)alloc((size_t)L_*DD*2);
    unsigned short* w1T  = (unsigned short*)alloc((size_t)L_*D_*F_*2);
    unsigned short* w2T  = (unsigned short*)alloc((size_t)L_*D_*F_*2);
    unsigned short* winT = (unsigned short*)alloc((size_t)D_*IN_*2);
    unsigned short* x_bf = (unsigned short*)alloc((size_t)BS_*IN_*2);
    unsigned short* hbuf = (unsigned short*)alloc((size_t)BS_*D_*2);    // bf16 residual stream
    unsigned short* y_bf = (unsigned short*)alloc((size_t)BS_*D_*2);
    unsigned short* qkvg = (unsigned short*)alloc((size_t)BS_*D2_*2);
    unsigned short* vTb  = (unsigned short*)alloc((size_t)BS_*D_*2);
    float*          cost = (float*)alloc((size_t)S_*DK_*4);
    float*          sint = (float*)alloc((size_t)S_*DK_*4);
    float*          dnrm = (float*)alloc((size_t)H_*S_*4);
    unsigned short* attn = y_bf;   // alias: y_bf dead after qkvg GEMM, rewritten by ln2 later
    unsigned short* midb = qkvg;   // alias: qkvg dead after retention

    dim3 tb(32, 8);

    // prep
    f32_to_bf16_k<<<(BS_*IN_)/256, 256, 0, stream>>>(x, x_bf, BS_*IN_);
    transpose_w_k<<<dim3(32,32,L_), tb, 0, stream>>>(Wq, wqkvgT + 0*DD, D_, D_, 4*DD);
    transpose_w_k<<<dim3(32,32,L_), tb, 0, stream>>>(Wk, wqkvgT + 1*DD, D_, D_, 4*DD);
    transpose_w_k<<<dim3(32,32,L_), tb, 0, stream>>>(Wv, wqkvgT + 2*DD, D_, D_, 4*DD);
    transpose_w_k<<<dim3(32,32,L_), tb, 0, stream>>>(Wg, wqkvgT + 3*DD, D_, D_, 4*DD);
    transpose_w_k<<<dim3(32,32,L_), tb, 0, stream>>>(Wo, woT, D_, D_, DD);
    transpose_w_k<<<dim3(64,32,L_), tb, 0, stream>>>(W1, w1T, D_, F_, (size_t)D_*F_);
    transpose_w_k<<<dim3(32,64,L_), tb, 0, stream>>>(W2, w2T, F_, D_, (size_t)D_*F_);
    transpose_w_k<<<dim3(32, 4, 1), tb, 0, stream>>>(W_in, winT, IN_, D_, (size_t)D_*IN_);
    build_sincos_k<<<(S_*64)/256, 256, 0, stream>>>(cost, sint);
    build_dnorm_k<<<(H_*S_)/256, 256, 0, stream>>>(dnrm);

    // input projection: h = x @ W_in + b_in   (K=128 -> NT=2)
    gemm6<0,128,128><<<dim3(D_/128, BS_/128), 512, 0, stream>>>(x_bf, winT, b_in, hbuf, BS_, D_, IN_);

    for (int l = 0; l < L_; ++l) {
        ln_to_bf16_k<<<BS_, 256, 0, stream>>>(hbuf, ln1s + l*D_, ln1b + l*D_, y_bf);
        gemm6<2,256,256><<<dim3(D2_/256, BS_/256), 512, 0, stream>>>(y_bf, wqkvgT + (size_t)l*4*DD, nullptr, qkvg, BS_, D2_, D_);
        rope_vt_k<<<dim3(S_/32, DK_/32, B_*H_), tb, 0, stream>>>(qkvg, vTb, cost, sint);
        retention_k<<<dim3(16, B_*H_), 256, 0, stream>>>(qkvg, vTb, dnrm, gn_g + l*D_, attn);
        gemm6<1,128,128><<<dim3(D_/128, BS_/128), 512, 0, stream>>>(attn, woT + (size_t)l*DD, nullptr, hbuf, BS_, D_, D_);
        ln_to_bf16_k<<<BS_, 256, 0, stream>>>(hbuf, ln2s + l*D_, ln2b + l*D_, y_bf);
        gemm6<3,128,128><<<dim3(F_/128, BS_/128), 512, 0, stream>>>(y_bf, w1T + (size_t)l*D_*F_, b1 + l*F_, midb, BS_, F_, D_);
        gemm6<1,128,128><<<dim3(D_/128, BS_/128), 512, 0, stream>>>(midb, w2T + (size_t)l*D_*F_, b2 + l*D_, hbuf, BS_, D_, F_);
    }

    head_out_k<<<BS_, 256, 0, stream>>>(hbuf, lnfs, lnfb, Wreg, breg, (float*)d_out);
}